// Round 1
// baseline (248.448 us; speedup 1.0000x reference)
//
#include <hip/hip_runtime.h>
#include <stdint.h>
#include <math.h>

typedef __bf16 bf16x8 __attribute__((ext_vector_type(8)));
typedef float f32x4 __attribute__((ext_vector_type(4)));
typedef unsigned short u16x8 __attribute__((ext_vector_type(8)));

__device__ __forceinline__ unsigned short f32_to_bf16_rne(float f) {
    unsigned u = __builtin_bit_cast(unsigned, f);
    u += 0x7fffu + ((u >> 16) & 1u);
    return (unsigned short)(u >> 16);
}

// ---------------------------------------------------------------------------
// int8 symmetric group-wise fake-quant, group size 128 along contiguous axis.
// 32 lanes per group, 4 elements (one float4) per lane. Output = bf16(q*scale).
// Masks 1..16 in a 64-wide shfl_xor reduce independently within each 32-lane
// half, which is exactly one group per half-wave.
// ---------------------------------------------------------------------------
__global__ __launch_bounds__(256) void quant_fake_int8_kernel(
    const float* __restrict__ in, unsigned short* __restrict__ out,
    long long n) {
    long long t = (long long)blockIdx.x * 256 + threadIdx.x;
    long long base = t * 4;
    if (base >= n) return;
    const float4 v = *reinterpret_cast<const float4*>(in + base);
    float m = fmaxf(fmaxf(fabsf(v.x), fabsf(v.y)),
                    fmaxf(fabsf(v.z), fabsf(v.w)));
#pragma unroll
    for (int off = 1; off <= 16; off <<= 1)
        m = fmaxf(m, __shfl_xor(m, off, 64));
    const float scale = fmaxf(m / 127.0f, 1e-8f);
    const float d0 = fminf(fmaxf(rintf(v.x / scale), -128.0f), 127.0f) * scale;
    const float d1 = fminf(fmaxf(rintf(v.y / scale), -128.0f), 127.0f) * scale;
    const float d2 = fminf(fmaxf(rintf(v.z / scale), -128.0f), 127.0f) * scale;
    const float d3 = fminf(fmaxf(rintf(v.w / scale), -128.0f), 127.0f) * scale;
    ushort4 o;
    o.x = f32_to_bf16_rne(d0);
    o.y = f32_to_bf16_rne(d1);
    o.z = f32_to_bf16_rne(d2);
    o.w = f32_to_bf16_rne(d3);
    *reinterpret_cast<ushort4*>(out + base) = o;
}

// ---------------------------------------------------------------------------
// bf16 GEMM, C[M][N] = A[M][K] * B[N][K]^T  (m97 structure: 128x128 tile,
// BK=32, 4 waves x (64x64) sub-tiles, global_load_lds width-16 staging,
// single LDS buffer, 2 barriers per K-step, mfma_f32_16x16x32_bf16).
// ---------------------------------------------------------------------------
#define BM 128
#define BN 128
#define BK 32

__device__ __forceinline__ void gload_lds16(const unsigned short* g,
                                            unsigned short* l) {
    __builtin_amdgcn_global_load_lds(
        (__attribute__((address_space(1))) void*)(g),
        (__attribute__((address_space(3))) void*)(l), 16, 0, 0);
}

__global__ __launch_bounds__(256) void gemm_bf16_bt(
    const unsigned short* __restrict__ A,  // [M][K] bf16 bits
    const unsigned short* __restrict__ B,  // [N][K] bf16 bits
    float* __restrict__ C,                 // [M][N]
    int M, int N, int K) {
    __shared__ __align__(16) unsigned short As[BM * BK];  // 8 KB
    __shared__ __align__(16) unsigned short Bs[BN * BK];  // 8 KB

    const int tid  = threadIdx.x;
    const int lane = tid & 63;
    const int wid  = tid >> 6;       // 0..3
    const int wr   = wid >> 1;       // wave row (0..1)
    const int wc   = wid & 1;        // wave col (0..1)

    const int tileM = blockIdx.y * BM;
    const int tileN = blockIdx.x * BN;

    // staging: lane covers row (lane>>2) of a 16-row chunk, 16B at col (lane&3)*8
    const int lrow = lane >> 2;        // 0..15
    const int lcol = (lane & 3) * 8;   // k-element offset: 0,8,16,24

    f32x4 acc[4][4] = {};

    for (int k0 = 0; k0 < K; k0 += BK) {
        // ---- stage A and B tiles into LDS (linear layout, wave-uniform dest)
#pragma unroll
        for (int j = 0; j < 2; ++j) {
            const int c = j * 4 + wid;          // chunk 0..7 -> rows c*16..+15
            const int r = c * 16 + lrow;
            gload_lds16(A + (size_t)(tileM + r) * K + (k0 + lcol),
                        &As[c * 512]);
            gload_lds16(B + (size_t)(tileN + r) * K + (k0 + lcol),
                        &Bs[c * 512]);
        }
        __syncthreads();  // compiler drains vmcnt(0) before s_barrier

        // ---- fragments: lane reads row (lane&15), 8 contiguous k at (lane>>4)*8
        bf16x8 a[4], b[4];
#pragma unroll
        for (int m = 0; m < 4; ++m) {
            const int row = wr * 64 + m * 16 + (lane & 15);
            a[m] = __builtin_bit_cast(
                bf16x8, *reinterpret_cast<const u16x8*>(
                            &As[row * BK + (lane >> 4) * 8]));
        }
#pragma unroll
        for (int n = 0; n < 4; ++n) {
            const int row = wc * 64 + n * 16 + (lane & 15);
            b[n] = __builtin_bit_cast(
                bf16x8, *reinterpret_cast<const u16x8*>(
                            &Bs[row * BK + (lane >> 4) * 8]));
        }
#pragma unroll
        for (int m = 0; m < 4; ++m)
#pragma unroll
            for (int n = 0; n < 4; ++n)
                acc[m][n] = __builtin_amdgcn_mfma_f32_16x16x32_bf16(
                    a[m], b[n], acc[m][n], 0, 0, 0);
        __syncthreads();
    }

    // ---- epilogue: C/D layout col = lane&15, row = (lane>>4)*4 + reg
    const int c0 = tileN + wc * 64 + (lane & 15);
    const int r0 = tileM + wr * 64 + (lane >> 4) * 4;
#pragma unroll
    for (int m = 0; m < 4; ++m)
#pragma unroll
        for (int n = 0; n < 4; ++n)
#pragma unroll
            for (int r = 0; r < 4; ++r)
                C[(size_t)(r0 + m * 16 + r) * N + (c0 + n * 16)] =
                    acc[m][n][r];
}

// ---------------------------------------------------------------------------
extern "C" void kernel_launch(void* const* d_in, const int* in_sizes, int n_in,
                              void* d_out, int out_size, void* d_ws,
                              size_t ws_size, hipStream_t stream) {
    const float* x = (const float*)d_in[0];   // [B,S,IN]  f32
    const float* w = (const float*)d_in[1];   // [OUT,IN]  f32
    float* out = (float*)d_out;               // [B,S,OUT] f32

    const long long MK = (long long)in_sizes[0];
    const long long NK = (long long)in_sizes[1];
    const long long MN = (long long)out_size;
    const long long K  = (long long)(sqrt((double)MK * (double)NK /
                                          (double)MN) + 0.5);
    const long long M  = MK / K;  // 16384
    const long long N  = NK / K;  // 2048

    unsigned short* qx = (unsigned short*)d_ws;       // M*K bf16
    unsigned short* qw = qx + MK;                     // N*K bf16

    // fake-quant both operands to bf16 (each thread = 4 elems, 32 lanes/group)
    quant_fake_int8_kernel<<<(int)(MK / 1024), 256, 0, stream>>>(x, qx, MK);
    quant_fake_int8_kernel<<<(int)(NK / 1024), 256, 0, stream>>>(w, qw, NK);

    dim3 grid((int)(N / BN), (int)(M / BM));
    gemm_bf16_bt<<<grid, 256, 0, stream>>>(qx, qw, out,
                                           (int)M, (int)N, (int)K);
}

// Round 2
// 183.247 us; speedup vs baseline: 1.3558x; 1.3558x over previous
//
#include <hip/hip_runtime.h>
#include <stdint.h>
#include <math.h>

typedef __bf16 bf16x8 __attribute__((ext_vector_type(8)));
typedef float f32x4 __attribute__((ext_vector_type(4)));
typedef unsigned short u16x8 __attribute__((ext_vector_type(8)));

__device__ __forceinline__ unsigned short f32_to_bf16_rne(float f) {
    unsigned u = __builtin_bit_cast(unsigned, f);
    u += 0x7fffu + ((u >> 16) & 1u);
    return (unsigned short)(u >> 16);
}

// ---------------------------------------------------------------------------
// int8 symmetric group-wise fake-quant, group 128 along contiguous axis.
// 32 lanes per group, one float4 per lane. Output = bf16(q*scale).
// Measured at HBM BW roofline (~37 us for both) — unchanged from round 1.
// ---------------------------------------------------------------------------
__global__ __launch_bounds__(256) void quant_fake_int8_kernel(
    const float* __restrict__ in, unsigned short* __restrict__ out,
    long long n) {
    long long t = (long long)blockIdx.x * 256 + threadIdx.x;
    long long base = t * 4;
    if (base >= n) return;
    const float4 v = *reinterpret_cast<const float4*>(in + base);
    float m = fmaxf(fmaxf(fabsf(v.x), fabsf(v.y)),
                    fmaxf(fabsf(v.z), fabsf(v.w)));
#pragma unroll
    for (int off = 1; off <= 16; off <<= 1)
        m = fmaxf(m, __shfl_xor(m, off, 64));
    const float scale = fmaxf(m / 127.0f, 1e-8f);
    const float d0 = fminf(fmaxf(rintf(v.x / scale), -128.0f), 127.0f) * scale;
    const float d1 = fminf(fmaxf(rintf(v.y / scale), -128.0f), 127.0f) * scale;
    const float d2 = fminf(fmaxf(rintf(v.z / scale), -128.0f), 127.0f) * scale;
    const float d3 = fminf(fmaxf(rintf(v.w / scale), -128.0f), 127.0f) * scale;
    ushort4 o;
    o.x = f32_to_bf16_rne(d0);
    o.y = f32_to_bf16_rne(d1);
    o.z = f32_to_bf16_rne(d2);
    o.w = f32_to_bf16_rne(d3);
    *reinterpret_cast<ushort4*>(out + base) = o;
}

// ---------------------------------------------------------------------------
// 256x256 8-phase bf16 GEMM (T2 swizzle + T3/T4 counted-vmcnt + T5 setprio).
// C[M][N] = A[M][K] * B[N][K]^T.  512 threads = 8 waves (2 Mx4 N),
// per-wave output 128x64. BK=64 -> 64 MFMA per K-tile per wave, 16/phase.
// LDS: 2 buffers x (A 32KB + B 32KB) = 128 KB.
// Swizzle: logical [row][colbyte] lives at LDS colbyte ^ ((row&7)<<4);
// global_load_lds writes linearly, so the SOURCE address is pre-swizzled
// (same involution), reads apply the XOR (both-sides rule, m231).
// vmcnt ledger: tile kt's 8 loads issued at phases 0/1 of kt-1. Phase 0 of
// kt issues kt+1's A-tile (4) -> 12 outstanding -> vmcnt(4) drains kt's 8.
// Phase 1 issues kt+1's B-tile. Never vmcnt(0) in steady state.
// ---------------------------------------------------------------------------
#define BM 256
#define BN 256
#define BKT 64

__device__ __forceinline__ void stage_tile(const unsigned short* __restrict__ G,
                                           unsigned short* L, int tid,
                                           int baseRow, int K, int k0) {
    // tile = [256][64] bf16, 128 B/row. 4 loads x 512 thr x 16 B = 32 KB.
    const int srow = tid >> 3;                                  // + i*64
    const int scb = (((tid & 7) << 4) ^ ((srow & 7) << 4)) >> 1; // elem col
#pragma unroll
    for (int i = 0; i < 4; ++i) {
        const int row = i * 64 + srow;
        __builtin_amdgcn_global_load_lds(
            (const __attribute__((address_space(1))) void*)(
                G + (size_t)(baseRow + row) * K + k0 + scb),
            (__attribute__((address_space(3))) void*)(
                L + i * 4096 + (tid >> 6) * 512),
            16, 0, 0);
    }
}

#define LDF(BASE, ROW, COE)                                      \
    __builtin_bit_cast(bf16x8, *reinterpret_cast<const u16x8*>(  \
                                   (BASE) + (((ROW) << 6) + (COE))))

template <int P>
__device__ __forceinline__ void mfma_quad(f32x4 (&acc)[8][4],
                                          const bf16x8 (&b0)[4],
                                          const bf16x8 (&b1)[4], bf16x8 a00,
                                          bf16x8 a01, bf16x8 a10, bf16x8 a11) {
#pragma unroll
    for (int n = 0; n < 4; ++n) {
        acc[2 * P][n] = __builtin_amdgcn_mfma_f32_16x16x32_bf16(
            a00, b0[n], acc[2 * P][n], 0, 0, 0);
        acc[2 * P][n] = __builtin_amdgcn_mfma_f32_16x16x32_bf16(
            a01, b1[n], acc[2 * P][n], 0, 0, 0);
        acc[2 * P + 1][n] = __builtin_amdgcn_mfma_f32_16x16x32_bf16(
            a10, b0[n], acc[2 * P + 1][n], 0, 0, 0);
        acc[2 * P + 1][n] = __builtin_amdgcn_mfma_f32_16x16x32_bf16(
            a11, b1[n], acc[2 * P + 1][n], 0, 0, 0);
    }
}

__global__ __launch_bounds__(512, 2) void gemm_bf16_8phase(
    const unsigned short* __restrict__ A,  // [M][K] bf16 bits
    const unsigned short* __restrict__ B,  // [N][K] bf16 bits
    float* __restrict__ C,                 // [M][N]
    int M, int N, int K) {
    __shared__ __align__(16) unsigned short lds[2][2][BM * BKT];  // 128 KB

    const int tid = threadIdx.x;
    const int lane = tid & 63;
    const int wid = tid >> 6;
    const int wr = wid >> 2;  // 0..1  (M half)
    const int wc = wid & 3;   // 0..3  (N quarter)
    const int l15 = lane & 15;
    const int lh = lane >> 4;
    const int swz = (lane & 7) << 4;
    const int coe0 = (((lh << 4)) ^ swz) >> 1;        // kk=0 elem col
    const int coe1 = (((lh << 4) | 64) ^ swz) >> 1;   // kk=1 elem col
    const int ra = wr * 128 + l15;                    // + m*16
    const int rb = wc * 64 + l15;                     // + n*16

    const int tileM = blockIdx.y * BM;
    const int tileN = blockIdx.x * BN;

    f32x4 acc[8][4] = {};
    bf16x8 b0[4], b1[4];

    const int NT = K >> 6;  // 32

    // prologue: stage tile 0 into buf 0 (8 loads outstanding)
    stage_tile(A, &lds[0][0][0], tid, tileM, K, 0);
    stage_tile(B, &lds[0][1][0], tid, tileN, K, 0);

    for (int kt = 0; kt < NT; ++kt) {
        const unsigned short* Ab = &lds[kt & 1][0][0];
        const unsigned short* Bb = &lds[kt & 1][1][0];
        unsigned short* An = &lds[(kt & 1) ^ 1][0][0];
        unsigned short* Bn = &lds[(kt & 1) ^ 1][1][0];
        const int k1 = (kt + 1) << 6;
        const bool pf = (kt + 1 < NT);

        // ---------------- phase 0: all B frags + A m0,m1 ----------------
        if (pf) {
            stage_tile(A, An, tid, tileM, K, k1);  // kt+1 A: 4 loads
            asm volatile("s_waitcnt vmcnt(4)" ::: "memory");
        } else {
            asm volatile("s_waitcnt vmcnt(0)" ::: "memory");
        }
        __builtin_amdgcn_s_barrier();  // buf[kt&1] now visible to all waves
        {
            bf16x8 a00 = LDF(Ab, ra + 0, coe0), a01 = LDF(Ab, ra + 0, coe1);
            bf16x8 a10 = LDF(Ab, ra + 16, coe0), a11 = LDF(Ab, ra + 16, coe1);
#pragma unroll
            for (int n = 0; n < 4; ++n) {
                b0[n] = LDF(Bb, rb + n * 16, coe0);
                b1[n] = LDF(Bb, rb + n * 16, coe1);
            }
            __builtin_amdgcn_s_barrier();
            __builtin_amdgcn_s_setprio(1);
            mfma_quad<0>(acc, b0, b1, a00, a01, a10, a11);
            __builtin_amdgcn_s_setprio(0);
            __builtin_amdgcn_s_barrier();
        }
        // ---------------- phase 1: A m2,m3 (+ stage B of kt+1) -----------
        {
            if (pf) stage_tile(B, Bn, tid, tileN, K, k1);
            bf16x8 a00 = LDF(Ab, ra + 32, coe0), a01 = LDF(Ab, ra + 32, coe1);
            bf16x8 a10 = LDF(Ab, ra + 48, coe0), a11 = LDF(Ab, ra + 48, coe1);
            __builtin_amdgcn_s_barrier();
            __builtin_amdgcn_s_setprio(1);
            mfma_quad<1>(acc, b0, b1, a00, a01, a10, a11);
            __builtin_amdgcn_s_setprio(0);
            __builtin_amdgcn_s_barrier();
        }
        // ---------------- phase 2: A m4,m5 -------------------------------
        {
            bf16x8 a00 = LDF(Ab, ra + 64, coe0), a01 = LDF(Ab, ra + 64, coe1);
            bf16x8 a10 = LDF(Ab, ra + 80, coe0), a11 = LDF(Ab, ra + 80, coe1);
            __builtin_amdgcn_s_barrier();
            __builtin_amdgcn_s_setprio(1);
            mfma_quad<2>(acc, b0, b1, a00, a01, a10, a11);
            __builtin_amdgcn_s_setprio(0);
            __builtin_amdgcn_s_barrier();
        }
        // ---------------- phase 3: A m6,m7 -------------------------------
        {
            bf16x8 a00 = LDF(Ab, ra + 96, coe0), a01 = LDF(Ab, ra + 96, coe1);
            bf16x8 a10 = LDF(Ab, ra + 112, coe0), a11 = LDF(Ab, ra + 112, coe1);
            __builtin_amdgcn_s_barrier();
            __builtin_amdgcn_s_setprio(1);
            mfma_quad<3>(acc, b0, b1, a00, a01, a10, a11);
            __builtin_amdgcn_s_setprio(0);
            __builtin_amdgcn_s_barrier();
        }
    }

    // ---- epilogue: C/D layout col = lane&15, row = (lane>>4)*4 + reg ----
    const int c0 = tileN + wc * 64 + l15;
    const int r0 = tileM + wr * 128 + lh * 4;
#pragma unroll
    for (int m = 0; m < 8; ++m)
#pragma unroll
        for (int n = 0; n < 4; ++n)
#pragma unroll
            for (int r = 0; r < 4; ++r)
                C[(size_t)(r0 + m * 16 + r) * N + (c0 + n * 16)] =
                    acc[m][n][r];
}

// ---------------------------------------------------------------------------
extern "C" void kernel_launch(void* const* d_in, const int* in_sizes, int n_in,
                              void* d_out, int out_size, void* d_ws,
                              size_t ws_size, hipStream_t stream) {
    const float* x = (const float*)d_in[0];  // [B,S,IN]  f32
    const float* w = (const float*)d_in[1];  // [OUT,IN]  f32
    float* out = (float*)d_out;              // [B,S,OUT] f32

    const long long MK = (long long)in_sizes[0];
    const long long NK = (long long)in_sizes[1];
    const long long MN = (long long)out_size;
    const long long K =
        (long long)(sqrt((double)MK * (double)NK / (double)MN) + 0.5);
    const long long M = MK / K;  // 16384
    const long long N = NK / K;  // 2048

    unsigned short* qx = (unsigned short*)d_ws;  // M*K bf16
    unsigned short* qw = qx + MK;                // N*K bf16

    quant_fake_int8_kernel<<<(int)(MK / 1024), 256, 0, stream>>>(x, qx, MK);
    quant_fake_int8_kernel<<<(int)(NK / 1024), 256, 0, stream>>>(w, qw, NK);

    dim3 grid((int)(N / BN), (int)(M / BM));  // (8, 64) = 512 blocks
    gemm_bf16_8phase<<<grid, 512, 0, stream>>>(qx, qw, out, (int)M, (int)N,
                                               (int)K);
}

// Round 3
// 176.728 us; speedup vs baseline: 1.4058x; 1.0369x over previous
//
#include <hip/hip_runtime.h>
#include <stdint.h>
#include <math.h>

typedef __bf16 bf16x8 __attribute__((ext_vector_type(8)));
typedef float f32x4 __attribute__((ext_vector_type(4)));
typedef unsigned short u16x8 __attribute__((ext_vector_type(8)));

__device__ __forceinline__ unsigned short f32_to_bf16_rne(float f) {
    unsigned u = __builtin_bit_cast(unsigned, f);
    u += 0x7fffu + ((u >> 16) & 1u);
    return (unsigned short)(u >> 16);
}

// ---------------------------------------------------------------------------
// int8 symmetric group-wise fake-quant, group 128 along contiguous axis.
// 32 lanes per group, one float4 per lane. Output = bf16(q*scale).
// At HBM BW roofline (~37 us for both) — unchanged.
// ---------------------------------------------------------------------------
__global__ __launch_bounds__(256) void quant_fake_int8_kernel(
    const float* __restrict__ in, unsigned short* __restrict__ out,
    long long n) {
    long long t = (long long)blockIdx.x * 256 + threadIdx.x;
    long long base = t * 4;
    if (base >= n) return;
    const float4 v = *reinterpret_cast<const float4*>(in + base);
    float m = fmaxf(fmaxf(fabsf(v.x), fabsf(v.y)),
                    fmaxf(fabsf(v.z), fabsf(v.w)));
#pragma unroll
    for (int off = 1; off <= 16; off <<= 1)
        m = fmaxf(m, __shfl_xor(m, off, 64));
    const float scale = fmaxf(m / 127.0f, 1e-8f);
    const float d0 = fminf(fmaxf(rintf(v.x / scale), -128.0f), 127.0f) * scale;
    const float d1 = fminf(fmaxf(rintf(v.y / scale), -128.0f), 127.0f) * scale;
    const float d2 = fminf(fmaxf(rintf(v.z / scale), -128.0f), 127.0f) * scale;
    const float d3 = fminf(fmaxf(rintf(v.w / scale), -128.0f), 127.0f) * scale;
    ushort4 o;
    o.x = f32_to_bf16_rne(d0);
    o.y = f32_to_bf16_rne(d1);
    o.z = f32_to_bf16_rne(d2);
    o.w = f32_to_bf16_rne(d3);
    *reinterpret_cast<ushort4*>(out + base) = o;
}

// ---------------------------------------------------------------------------
// Persistent 256x256 8-phase bf16 GEMM. C[M][N] = A[M][K] * B[N][K]^T.
// 256 blocks (1/CU), each computes TWO 256x256 tiles sharing the same
// N-panel (ty and ty+32). XCD-chunked block remap: id=(b%8)*32+b/8 so each
// XCD's 32 blocks cover 4 A-panels x 8 N-tiles (A fits its 4MB L2).
// t1's first K-tile is staged BEFORE the t0 epilogue: the C-store burst
// hides the prologue HBM latency; vmcnt in-order retirement keeps the
// vmcnt(4) ledger exact (drains 8 prologue loads + all stores, leaves the
// 4 freshly issued A-loads in flight).
// LDS swizzle: logical [row][colbyte] at colbyte ^ ((row&7)<<4), applied to
// the pre-swizzled global SOURCE of global_load_lds and to ds_read addrs
// (both-sides rule). Verified round 2: bank conflicts = 0.
// ---------------------------------------------------------------------------
#define BM 256
#define BN 256
#define BKT 64

__device__ __forceinline__ void stage_tile(const unsigned short* __restrict__ G,
                                           unsigned short* L, int tid,
                                           int baseRow, int K, int k0) {
    // tile = [256][64] bf16, 128 B/row. 4 loads x 512 thr x 16 B = 32 KB.
    const int srow = tid >> 3;                                   // + i*64
    const int scb = (((tid & 7) << 4) ^ ((srow & 7) << 4)) >> 1; // elem col
#pragma unroll
    for (int i = 0; i < 4; ++i) {
        const int row = i * 64 + srow;
        __builtin_amdgcn_global_load_lds(
            (const __attribute__((address_space(1))) void*)(
                G + (size_t)(baseRow + row) * K + k0 + scb),
            (__attribute__((address_space(3))) void*)(
                L + i * 4096 + (tid >> 6) * 512),
            16, 0, 0);
    }
}

#define LDF(BASE, ROW, COE)                                      \
    __builtin_bit_cast(bf16x8, *reinterpret_cast<const u16x8*>(  \
                                   (BASE) + (((ROW) << 6) + (COE))))

template <int P>
__device__ __forceinline__ void mfma_quad(f32x4 (&acc)[8][4],
                                          const bf16x8 (&b0)[4],
                                          const bf16x8 (&b1)[4], bf16x8 a00,
                                          bf16x8 a01, bf16x8 a10, bf16x8 a11) {
#pragma unroll
    for (int n = 0; n < 4; ++n) {
        acc[2 * P][n] = __builtin_amdgcn_mfma_f32_16x16x32_bf16(
            a00, b0[n], acc[2 * P][n], 0, 0, 0);
        acc[2 * P][n] = __builtin_amdgcn_mfma_f32_16x16x32_bf16(
            a01, b1[n], acc[2 * P][n], 0, 0, 0);
        acc[2 * P + 1][n] = __builtin_amdgcn_mfma_f32_16x16x32_bf16(
            a10, b0[n], acc[2 * P + 1][n], 0, 0, 0);
        acc[2 * P + 1][n] = __builtin_amdgcn_mfma_f32_16x16x32_bf16(
            a11, b1[n], acc[2 * P + 1][n], 0, 0, 0);
    }
}

__global__ __launch_bounds__(512, 2) void gemm_bf16_8phase(
    const unsigned short* __restrict__ A,  // [M][K] bf16 bits
    const unsigned short* __restrict__ B,  // [N][K] bf16 bits
    float* __restrict__ C,                 // [M][N]
    int M, int N, int K) {
    __shared__ __align__(16) unsigned short lds[2][2][BM * BKT];  // 128 KB

    const int tid = threadIdx.x;
    const int lane = tid & 63;
    const int wid = tid >> 6;
    const int wr = wid >> 2;  // 0..1  (M half)
    const int wc = wid & 3;   // 0..3  (N quarter)
    const int l15 = lane & 15;
    const int lh = lane >> 4;
    const int swz = (lane & 7) << 4;
    const int coe0 = (((lh << 4)) ^ swz) >> 1;       // kk=0 elem col
    const int coe1 = (((lh << 4) | 64) ^ swz) >> 1;  // kk=1 elem col
    const int ra = wr * 128 + l15;                   // + m*16
    const int rb = wc * 64 + l15;                    // + n*16

    // XCD-chunked remap: id = (b%8)*32 + b/8; tx = id%8, ty = id/8 (0..31).
    const int id = (blockIdx.x & 7) * 32 + (blockIdx.x >> 3);
    const int tileN = (id & 7) * BN;
    const int tyBase = id >> 3;  // 0..31; tiles ty and ty+32

    const int NT = K >> 6;  // 32

    // prologue for tile pair member 0
    stage_tile(A, &lds[0][0][0], tid, tyBase * BM, K, 0);
    stage_tile(B, &lds[0][1][0], tid, tileN, K, 0);

#pragma unroll 1
    for (int t = 0; t < 2; ++t) {
        const int tileM = (tyBase + t * 32) * BM;
        f32x4 acc[8][4] = {};
        bf16x8 b0[4], b1[4];

#pragma unroll 1
        for (int kt = 0; kt < NT; ++kt) {
            const unsigned short* Ab = &lds[kt & 1][0][0];
            const unsigned short* Bb = &lds[kt & 1][1][0];
            unsigned short* An = &lds[(kt & 1) ^ 1][0][0];
            unsigned short* Bn = &lds[(kt & 1) ^ 1][1][0];
            const int k1 = (kt + 1) << 6;
            const bool pf = (kt + 1 < NT);

            // ------------- phase 0: all B frags + A m0,m1 -------------
            if (pf) {
                stage_tile(A, An, tid, tileM, K, k1);  // kt+1 A: 4 loads
                asm volatile("s_waitcnt vmcnt(4)" ::: "memory");
            } else {
                asm volatile("s_waitcnt vmcnt(0)" ::: "memory");
            }
            __builtin_amdgcn_s_barrier();  // buf[kt&1] visible to all waves
            {
                bf16x8 a00 = LDF(Ab, ra + 0, coe0),
                       a01 = LDF(Ab, ra + 0, coe1);
                bf16x8 a10 = LDF(Ab, ra + 16, coe0),
                       a11 = LDF(Ab, ra + 16, coe1);
#pragma unroll
                for (int n = 0; n < 4; ++n) {
                    b0[n] = LDF(Bb, rb + n * 16, coe0);
                    b1[n] = LDF(Bb, rb + n * 16, coe1);
                }
                __builtin_amdgcn_s_barrier();
                __builtin_amdgcn_s_setprio(1);
                mfma_quad<0>(acc, b0, b1, a00, a01, a10, a11);
                __builtin_amdgcn_s_setprio(0);
                __builtin_amdgcn_s_barrier();
            }
            // ------------- phase 1: A m2,m3 (+ stage kt+1 B) -----------
            {
                if (pf) stage_tile(B, Bn, tid, tileN, K, k1);
                bf16x8 a00 = LDF(Ab, ra + 32, coe0),
                       a01 = LDF(Ab, ra + 32, coe1);
                bf16x8 a10 = LDF(Ab, ra + 48, coe0),
                       a11 = LDF(Ab, ra + 48, coe1);
                __builtin_amdgcn_s_barrier();
                __builtin_amdgcn_s_setprio(1);
                mfma_quad<1>(acc, b0, b1, a00, a01, a10, a11);
                __builtin_amdgcn_s_setprio(0);
                __builtin_amdgcn_s_barrier();
            }
            // ------------- phase 2: A m4,m5 ----------------------------
            {
                bf16x8 a00 = LDF(Ab, ra + 64, coe0),
                       a01 = LDF(Ab, ra + 64, coe1);
                bf16x8 a10 = LDF(Ab, ra + 80, coe0),
                       a11 = LDF(Ab, ra + 80, coe1);
                __builtin_amdgcn_s_barrier();
                __builtin_amdgcn_s_setprio(1);
                mfma_quad<2>(acc, b0, b1, a00, a01, a10, a11);
                __builtin_amdgcn_s_setprio(0);
                __builtin_amdgcn_s_barrier();
            }
            // ------------- phase 3: A m6,m7 ----------------------------
            {
                bf16x8 a00 = LDF(Ab, ra + 96, coe0),
                       a01 = LDF(Ab, ra + 96, coe1);
                bf16x8 a10 = LDF(Ab, ra + 112, coe0),
                       a11 = LDF(Ab, ra + 112, coe1);
                __builtin_amdgcn_s_barrier();
                __builtin_amdgcn_s_setprio(1);
                mfma_quad<3>(acc, b0, b1, a00, a01, a10, a11);
                __builtin_amdgcn_s_setprio(0);
                __builtin_amdgcn_s_barrier();
            }
        }

        // stage tile-pair member 1's first K-tile BEFORE the epilogue:
        // the C-store burst below hides this prologue's HBM latency.
        // (buf[0] was last consumed at kt = NT-2; every wave's reads of it
        // completed before the kt = NT-1 visibility barrier.)
        if (t == 0) {
            stage_tile(A, &lds[0][0][0], tid, (tyBase + 32) * BM, K, 0);
            stage_tile(B, &lds[0][1][0], tid, tileN, K, 0);
        }

        // ---- epilogue: C/D layout col = lane&15, row = (lane>>4)*4+reg;
        // nontemporal stores keep A/B panels resident in L2.
        const int c0 = tileN + wc * 64 + l15;
        const int r0 = tileM + wr * 128 + lh * 4;
#pragma unroll
        for (int m = 0; m < 8; ++m)
#pragma unroll
            for (int n = 0; n < 4; ++n)
#pragma unroll
                for (int r = 0; r < 4; ++r)
                    __builtin_nontemporal_store(
                        acc[m][n][r],
                        &C[(size_t)(r0 + m * 16 + r) * N + (c0 + n * 16)]);
    }
}

// ---------------------------------------------------------------------------
extern "C" void kernel_launch(void* const* d_in, const int* in_sizes, int n_in,
                              void* d_out, int out_size, void* d_ws,
                              size_t ws_size, hipStream_t stream) {
    const float* x = (const float*)d_in[0];  // [B,S,IN]  f32
    const float* w = (const float*)d_in[1];  // [OUT,IN]  f32
    float* out = (float*)d_out;              // [B,S,OUT] f32

    const long long MK = (long long)in_sizes[0];
    const long long NK = (long long)in_sizes[1];
    const long long MN = (long long)out_size;
    const long long K =
        (long long)(sqrt((double)MK * (double)NK / (double)MN) + 0.5);
    const long long M = MK / K;  // 16384
    const long long N = NK / K;  // 2048

    unsigned short* qx = (unsigned short*)d_ws;  // M*K bf16
    unsigned short* qw = qx + MK;                // N*K bf16

    quant_fake_int8_kernel<<<(int)(MK / 1024), 256, 0, stream>>>(x, qx, MK);
    quant_fake_int8_kernel<<<(int)(NK / 1024), 256, 0, stream>>>(w, qw, NK);

    // 256 persistent blocks (1/CU), each computes 2 tiles (ty, ty+32) x tx.
    gemm_bf16_8phase<<<256, 512, 0, stream>>>(qx, qw, out, (int)M, (int)N,
                                              (int)K);
}

// Round 4
// 173.044 us; speedup vs baseline: 1.4358x; 1.0213x over previous
//
#include <hip/hip_runtime.h>
#include <stdint.h>
#include <math.h>

typedef __bf16 bf16x8 __attribute__((ext_vector_type(8)));
typedef float f32x4 __attribute__((ext_vector_type(4)));
typedef unsigned short u16x8 __attribute__((ext_vector_type(8)));

__device__ __forceinline__ unsigned short f32_to_bf16_rne(float f) {
    unsigned u = __builtin_bit_cast(unsigned, f);
    u += 0x7fffu + ((u >> 16) & 1u);
    return (unsigned short)(u >> 16);
}

// ---------------------------------------------------------------------------
// int8 symmetric group-wise fake-quant, group 128 along contiguous axis.
// 32 lanes per group, one float4 per lane. Output = bf16(q*scale).
// At HBM BW roofline — unchanged.
// ---------------------------------------------------------------------------
__global__ __launch_bounds__(256) void quant_fake_int8_kernel(
    const float* __restrict__ in, unsigned short* __restrict__ out,
    long long n) {
    long long t = (long long)blockIdx.x * 256 + threadIdx.x;
    long long base = t * 4;
    if (base >= n) return;
    const float4 v = *reinterpret_cast<const float4*>(in + base);
    float m = fmaxf(fmaxf(fabsf(v.x), fabsf(v.y)),
                    fmaxf(fabsf(v.z), fabsf(v.w)));
#pragma unroll
    for (int off = 1; off <= 16; off <<= 1)
        m = fmaxf(m, __shfl_xor(m, off, 64));
    const float scale = fmaxf(m / 127.0f, 1e-8f);
    const float d0 = fminf(fmaxf(rintf(v.x / scale), -128.0f), 127.0f) * scale;
    const float d1 = fminf(fmaxf(rintf(v.y / scale), -128.0f), 127.0f) * scale;
    const float d2 = fminf(fmaxf(rintf(v.z / scale), -128.0f), 127.0f) * scale;
    const float d3 = fminf(fmaxf(rintf(v.w / scale), -128.0f), 127.0f) * scale;
    ushort4 o;
    o.x = f32_to_bf16_rne(d0);
    o.y = f32_to_bf16_rne(d1);
    o.z = f32_to_bf16_rne(d2);
    o.w = f32_to_bf16_rne(d3);
    *reinterpret_cast<ushort4*>(out + base) = o;
}

// ---------------------------------------------------------------------------
// 256x256 bf16 GEMM, BK=32, ring-4 LDS, prefetch depth 3, counted vmcnt.
// C[M][N] = A[M][K] * B[N][K]^T.  512 thr = 8 waves (2M x 4N), per-wave
// output 128x64. Per K-tile: 2 phases x 16 independent MFMA.
// LDS: 4 ring slots x (A 16KB + B 16KB) = 128 KB.
// Swizzle (64B rows): logical colbyte cb of row r lives at cb ^ (((r>>1)&3)<<4)
// -> 16-lane column reads cover the 16x64B region exactly once (2-way max =
// free). Applied to pre-swizzled global SOURCE of global_load_lds (dest is
// linear) and to ds_read addresses — both-sides rule.
// vmcnt ledger (depth 3): tile kt's 4 loads issued at kt-3. At kt ph0:
// issue kt+3's A (2) -> outstanding = kt(4)+kt+1(4)+kt+2(4)+2 = 14;
// vmcnt(10) drains exactly kt's 4. ph1 issues kt+3's B. Tail: 8/4/0.
// Hazard check: writes to slot (kt+3)&3 == (kt-1)&3 issue after the kt ph0
// visibility barrier, i.e. >= 2 barriers after every wave's last read of
// that slot (kt-1 end-barrier) -> race-free.
// ---------------------------------------------------------------------------
#define BM 256
#define BN 256
#define BKT 32

__device__ __forceinline__ void stage32(const unsigned short* __restrict__ G,
                                        unsigned short* L, int tid,
                                        int baseRow, int K, int k0) {
    // tile = [256][32] bf16, 64 B/row. 2 loads x 512 thr x 16 B = 16 KB.
    const int r = tid >> 2;                                        // 0..127
    const int scb = (((tid & 3) << 4) ^ (((r >> 1) & 3) << 4)) >> 1;
#pragma unroll
    for (int i = 0; i < 2; ++i) {
        __builtin_amdgcn_global_load_lds(
            (const __attribute__((address_space(1))) void*)(
                G + (size_t)(baseRow + i * 128 + r) * K + k0 + scb),
            (__attribute__((address_space(3))) void*)(
                L + i * 4096 + (tid >> 6) * 512),
            16, 0, 0);
    }
}

#define LDF32(BASE, ROW)                                         \
    __builtin_bit_cast(bf16x8, *reinterpret_cast<const u16x8*>(  \
                                   (BASE) + (((ROW) << 5) + coe)))

__global__ __launch_bounds__(512, 2) void gemm_bf16_ring4(
    const unsigned short* __restrict__ A,  // [M][K] bf16 bits
    const unsigned short* __restrict__ B,  // [N][K] bf16 bits
    float* __restrict__ C,                 // [M][N]
    int M, int N, int K) {
    __shared__ __align__(16) unsigned short lds[4][2][BM * BKT];  // 128 KB

    const int tid = threadIdx.x;
    const int lane = tid & 63;
    const int wid = tid >> 6;
    const int wr = wid >> 2;  // 0..1  (M half)
    const int wc = wid & 3;   // 0..3  (N quarter)
    const int l15 = lane & 15;
    const int lh = lane >> 4;  // 0..3 = k-slot (16B each)
    // swizzle bits from the fragment row: (row>>1)&3 == (l15>>1)&3 for all
    // m/n offsets (multiples of 16) and wave bases (multiples of 64).
    const int coe = (((lh << 4) ^ (((l15 >> 1) & 3) << 4)) >> 1);
    const int ra = wr * 128 + l15;  // + m*16
    const int rb = wc * 64 + l15;   // + n*16

    // XCD-chunked bijective remap over 512 blocks (512 % 8 == 0).
    const int id = (blockIdx.x & 7) * 64 + (blockIdx.x >> 3);
    const int tileN = (id & 7) * BN;
    const int tileM = (id >> 3) * BM;

    const int NT = K >> 5;  // 64

    f32x4 acc[8][4] = {};
    bf16x8 b[4];

    // prologue: stage K-tiles 0,1,2 (12 loads outstanding)
    stage32(A, &lds[0][0][0], tid, tileM, K, 0);
    stage32(B, &lds[0][1][0], tid, tileN, K, 0);
    stage32(A, &lds[1][0][0], tid, tileM, K, 32);
    stage32(B, &lds[1][1][0], tid, tileN, K, 32);
    stage32(A, &lds[2][0][0], tid, tileM, K, 64);
    stage32(B, &lds[2][1][0], tid, tileN, K, 64);

#pragma unroll 1
    for (int kt = 0; kt < NT; ++kt) {
        const unsigned short* Ab = &lds[kt & 3][0][0];
        const unsigned short* Bb = &lds[kt & 3][1][0];
        unsigned short* An = &lds[(kt + 3) & 3][0][0];
        unsigned short* Bn = &lds[(kt + 3) & 3][1][0];
        const int k3 = (kt + 3) << 5;
        const bool pf = (kt + 3 < NT);

        // ---- phase 0: stage kt+3 A, drain kt, read B[0..3] + A[m0..3] ----
        if (pf) {
            stage32(A, An, tid, tileM, K, k3);
            asm volatile("s_waitcnt vmcnt(10)" ::: "memory");
        } else if (kt == NT - 3) {
            asm volatile("s_waitcnt vmcnt(8)" ::: "memory");
        } else if (kt == NT - 2) {
            asm volatile("s_waitcnt vmcnt(4)" ::: "memory");
        } else {
            asm volatile("s_waitcnt vmcnt(0)" ::: "memory");
        }
        __builtin_amdgcn_s_barrier();  // slot kt&3 visible to all waves
        {
            bf16x8 a0 = LDF32(Ab, ra + 0);
            bf16x8 a1 = LDF32(Ab, ra + 16);
            bf16x8 a2 = LDF32(Ab, ra + 32);
            bf16x8 a3 = LDF32(Ab, ra + 48);
#pragma unroll
            for (int n = 0; n < 4; ++n) b[n] = LDF32(Bb, rb + n * 16);
            __builtin_amdgcn_s_setprio(1);
#pragma unroll
            for (int n = 0; n < 4; ++n) {
                acc[0][n] = __builtin_amdgcn_mfma_f32_16x16x32_bf16(
                    a0, b[n], acc[0][n], 0, 0, 0);
                acc[1][n] = __builtin_amdgcn_mfma_f32_16x16x32_bf16(
                    a1, b[n], acc[1][n], 0, 0, 0);
                acc[2][n] = __builtin_amdgcn_mfma_f32_16x16x32_bf16(
                    a2, b[n], acc[2][n], 0, 0, 0);
                acc[3][n] = __builtin_amdgcn_mfma_f32_16x16x32_bf16(
                    a3, b[n], acc[3][n], 0, 0, 0);
            }
            __builtin_amdgcn_s_setprio(0);
        }
        // ---- phase 1: stage kt+3 B, read A[m4..7], MFMA ----
        {
            if (pf) stage32(B, Bn, tid, tileN, K, k3);
            bf16x8 a4 = LDF32(Ab, ra + 64);
            bf16x8 a5 = LDF32(Ab, ra + 80);
            bf16x8 a6 = LDF32(Ab, ra + 96);
            bf16x8 a7 = LDF32(Ab, ra + 112);
            __builtin_amdgcn_s_setprio(1);
#pragma unroll
            for (int n = 0; n < 4; ++n) {
                acc[4][n] = __builtin_amdgcn_mfma_f32_16x16x32_bf16(
                    a4, b[n], acc[4][n], 0, 0, 0);
                acc[5][n] = __builtin_amdgcn_mfma_f32_16x16x32_bf16(
                    a5, b[n], acc[5][n], 0, 0, 0);
                acc[6][n] = __builtin_amdgcn_mfma_f32_16x16x32_bf16(
                    a6, b[n], acc[6][n], 0, 0, 0);
                acc[7][n] = __builtin_amdgcn_mfma_f32_16x16x32_bf16(
                    a7, b[n], acc[7][n], 0, 0, 0);
            }
            __builtin_amdgcn_s_setprio(0);
            __builtin_amdgcn_s_barrier();  // K-tile end: bounds wave skew
        }
    }

    // ---- epilogue: C/D layout col = lane&15, row = (lane>>4)*4 + reg ----
    const int c0 = tileN + wc * 64 + l15;
    const int r0 = tileM + wr * 128 + lh * 4;
#pragma unroll
    for (int m = 0; m < 8; ++m)
#pragma unroll
        for (int n = 0; n < 4; ++n)
#pragma unroll
            for (int r = 0; r < 4; ++r)
                C[(size_t)(r0 + m * 16 + r) * N + (c0 + n * 16)] =
                    acc[m][n][r];
}

// ---------------------------------------------------------------------------
extern "C" void kernel_launch(void* const* d_in, const int* in_sizes, int n_in,
                              void* d_out, int out_size, void* d_ws,
                              size_t ws_size, hipStream_t stream) {
    const float* x = (const float*)d_in[0];  // [B,S,IN]  f32
    const float* w = (const float*)d_in[1];  // [OUT,IN]  f32
    float* out = (float*)d_out;              // [B,S,OUT] f32

    const long long MK = (long long)in_sizes[0];
    const long long NK = (long long)in_sizes[1];
    const long long MN = (long long)out_size;
    const long long K =
        (long long)(sqrt((double)MK * (double)NK / (double)MN) + 0.5);
    const long long M = MK / K;  // 16384
    const long long N = NK / K;  // 2048

    unsigned short* qx = (unsigned short*)d_ws;  // M*K bf16
    unsigned short* qw = qx + MK;                // N*K bf16

    quant_fake_int8_kernel<<<(int)(MK / 1024), 256, 0, stream>>>(x, qx, MK);
    quant_fake_int8_kernel<<<(int)(NK / 1024), 256, 0, stream>>>(w, qw, NK);

    dim3 grid(512);  // (M/256)*(N/256) = 64*8
    gemm_bf16_ring4<<<grid, 512, 0, stream>>>(qx, qw, out, (int)M, (int)N,
                                              (int)K);
}